// Round 5
// baseline (858.390 us; speedup 1.0000x reference)
//
#include <hip/hip_runtime.h>
#include <cstdint>
#include <cstddef>

#define BB 8
#define TT 1536
#define DD 512
#define HH 8
#define HDD 64
#define LL 4
#define MROWS (BB*TT)   // 12288

typedef __bf16 bf16;
typedef __bf16 bf16x8 __attribute__((ext_vector_type(8)));
typedef float f32x4 __attribute__((ext_vector_type(4)));

typedef void as1_void __attribute__((address_space(1)));
typedef void as3_void __attribute__((address_space(3)));

__device__ __forceinline__ void gload16(const bf16* g, bf16* l) {
  __builtin_amdgcn_global_load_lds((as1_void*)g, (as3_void*)l, 16, 0, 0);
}

__device__ __forceinline__ float gelu_f(float v) {
  return 0.5f * v * (1.0f + erff(v * 0.70710678118654752440f));
}

// ---------------- weight fp32 -> bf16 ----------------
__global__ void cvt_f2b(const float* __restrict__ in, bf16* __restrict__ out, int n4) {
  int i = blockIdx.x * blockDim.x + threadIdx.x;
  if (i >= n4) return;
  float4 v = ((const float4*)in)[i];
  union { bf16 h[4]; uint2 u; } p;
  p.h[0] = (bf16)v.x; p.h[1] = (bf16)v.y; p.h[2] = (bf16)v.z; p.h[3] = (bf16)v.w;
  ((uint2*)out)[i] = p.u;
}

// ---------------- sinusoidal PE table (T x D fp32) ----------------
__global__ void pe_kernel(float* __restrict__ pe) {
  int i = blockIdx.x * blockDim.x + threadIdx.x;   // over T*(D/2)
  if (i >= TT * (DD / 2)) return;
  int t = i / (DD / 2), k = i % (DD / 2);
  float div = expf((2.0f * (float)k) * (-9.210340371976184f / (float)DD));
  float ang = (float)t * div;
  pe[(size_t)t * DD + 2 * k]     = sinf(ang);
  pe[(size_t)t * DD + 2 * k + 1] = cosf(ang);
}

// ---------------- depthwise conv k=5 pad=2 (+bias) -> bf16, float4 ----------------
__global__ void conv_dw(const float* __restrict__ x, const float* __restrict__ kw,
                        const float* __restrict__ kb, bf16* __restrict__ out) {
  int idx = blockIdx.x * 256 + threadIdx.x;        // over B*T*(D/4)
  int d4 = idx & (DD / 4 - 1);
  int bt = idx >> 7;                               // D/4=128
  int t = bt % TT;
  float4 acc = ((const float4*)kb)[d4];
  #pragma unroll
  for (int w = 0; w < 5; ++w) {
    int tt = t + w - 2;
    if (tt >= 0 && tt < TT) {
      float4 xv = ((const float4*)(x + (size_t)(bt + (w - 2)) * DD))[d4];
      float4 kv = ((const float4*)(kw + w * DD))[d4];
      acc.x += xv.x * kv.x; acc.y += xv.y * kv.y;
      acc.z += xv.z * kv.z; acc.w += xv.w * kv.w;
    }
  }
  union { bf16 h[4]; uint2 u; } p;
  p.h[0] = (bf16)acc.x; p.h[1] = (bf16)acc.y; p.h[2] = (bf16)acc.z; p.h[3] = (bf16)acc.w;
  ((uint2*)out)[idx] = p.u;
}

// ---------------- LayerNorm (row=512) fp32 -> bf16, wave per row ----------------
__global__ __launch_bounds__(256) void ln_kernel(const float* __restrict__ x,
    const float* __restrict__ w, const float* __restrict__ b, bf16* __restrict__ y) {
  int l = threadIdx.x & 63;
  int row = blockIdx.x * 4 + (threadIdx.x >> 6);
  const float4* xr = (const float4*)(x + (size_t)row * DD);
  union F8 { float4 v[2]; float f[8]; };
  F8 xv, wv, bv;
  xv.v[0] = xr[l * 2]; xv.v[1] = xr[l * 2 + 1];
  float s = 0.f, q = 0.f;
  #pragma unroll
  for (int e = 0; e < 8; ++e) { s += xv.f[e]; q += xv.f[e] * xv.f[e]; }
  #pragma unroll
  for (int off = 1; off < 64; off <<= 1) {
    s += __shfl_xor(s, off);
    q += __shfl_xor(q, off);
  }
  float mean = s * (1.0f / DD);
  float var  = q * (1.0f / DD) - mean * mean;
  float rstd = rsqrtf(var + 1e-5f);
  const float4* wr = (const float4*)w;
  const float4* br = (const float4*)b;
  wv.v[0] = wr[l * 2]; wv.v[1] = wr[l * 2 + 1];
  bv.v[0] = br[l * 2]; bv.v[1] = br[l * 2 + 1];
  bf16x8 o;
  #pragma unroll
  for (int e = 0; e < 8; ++e)
    o[e] = (bf16)((xv.f[e] - mean) * rstd * wv.f[e] + bv.f[e]);
  *(bf16x8*)(y + (size_t)row * DD + l * 8) = o;
}

// ---------------- sliding-window attention ----------------
__global__ __launch_bounds__(256) void attn_kernel(const bf16* __restrict__ qkv,
    const unsigned char* __restrict__ pad, bf16* __restrict__ o) {
  int l = threadIdx.x & 63;
  int wv = blockIdx.x * 4 + (threadIdx.x >> 6);    // over B*H*(T/8)
  int g = l >> 3, s = l & 7;
  int tb = wv % (TT / 8);
  int bh = wv / (TT / 8);
  int h = bh & (HH - 1);
  int b = bh >> 3;
  int t = tb * 8 + g;
  const float scale = 0.125f;                      // 1/sqrt(64)
  const bf16* base = qkv + (size_t)(b * TT) * (3 * DD) + h * HDD + s * 8;

  float q[8];
  {
    bf16x8 qv = *(const bf16x8*)(base + (size_t)t * (3 * DD));
    #pragma unroll
    for (int e = 0; e < 8; ++e) q[e] = (float)qv[e] * scale;
  }
  float sc[11];
  #pragma unroll
  for (int jj = 0; jj < 11; ++jj) {
    int j = t - 5 + jj;
    bool ok = (j >= 0) && (j < TT);
    int jc = ok ? j : t;
    bf16x8 kv = *(const bf16x8*)(base + (size_t)jc * (3 * DD) + DD);
    float sv = 0.f;
    #pragma unroll
    for (int e = 0; e < 8; ++e) sv += q[e] * (float)kv[e];
    sv += __shfl_xor(sv, 1);
    sv += __shfl_xor(sv, 2);
    sv += __shfl_xor(sv, 4);
    if (pad[b * TT + jc]) sv -= 1e9f;
    sc[jj] = ok ? sv : -3.0e38f;
  }
  float m = sc[0];
  #pragma unroll
  for (int jj = 1; jj < 11; ++jj) m = fmaxf(m, sc[jj]);
  float den = 0.f;
  float acc[8] = {};
  #pragma unroll
  for (int jj = 0; jj < 11; ++jj) {
    float p = __expf(sc[jj] - m);
    den += p;
    int j = t - 5 + jj;
    int jc = (j >= 0 && j < TT) ? j : t;
    bf16x8 vv = *(const bf16x8*)(base + (size_t)jc * (3 * DD) + 2 * DD);
    #pragma unroll
    for (int e = 0; e < 8; ++e) acc[e] += p * (float)vv[e];
  }
  float rd = 1.0f / den;
  bf16x8 ov;
  #pragma unroll
  for (int e = 0; e < 8; ++e) ov[e] = (bf16)(acc[e] * rd);
  *(bf16x8*)(o + (size_t)(b * TT + t) * DD + h * HDD + s * 8) = ov;
}

// ---------------- bf16 MFMA GEMM: C = A[M][K] * Bw[N][K]^T (+epilogue) ----------------
// Tile BM x 128, BK=64, 4 waves (2x2). DBUF: 2-phase double-buffered staging.
// Epilogue goes through an LDS transpose so every wave writes contiguous >=256B runs.
// MODE 0: Cb = acc + bias                    (bf16 out)
// MODE 1: Cb = gelu(acc + bias)              (bf16 out)
// MODE 2: Cf += acc + bias                   (fp32 master, in-place RMW)
// MODE 3: Cf = resid + gelu(acc+bias) + pe   (fp32 master init; pointwise front-end)
template<int MODE, int BM, bool DBUF>
__global__ __launch_bounds__(256) void gemm_bt(
    const bf16* __restrict__ A, const bf16* __restrict__ Bw,
    const float* __restrict__ bias, const float* __restrict__ pe,
    const float* __restrict__ resid, float* __restrict__ Cf, bf16* __restrict__ Cb,
    int M, int N, int K)
{
  constexpr int RI = BM / 32;            // 16x16 row-fragments per wave
  constexpr int NB = DBUF ? 2 : 1;
  constexpr int STAGE_B = NB * (BM * 64 + 128 * 64) * 2;
  constexpr int EPS = 132;               // fp32 row stride in epilogue LDS
  constexpr int EP_B = 2 * 16 * EPS * 4;
  __shared__ __align__(16) char smem[(STAGE_B > EP_B) ? STAGE_B : EP_B];
  bf16* sA = (bf16*)smem;                         // sA buf b at sA + b*BM*64
  bf16* sB = (bf16*)smem + NB * BM * 64;          // sB buf b at sB + b*128*64
  float* ep = (float*)smem;                       // epilogue transpose buffer

  int tid = threadIdx.x;
  int w = tid >> 6, l = tid & 63;
  int wr = w >> 1, wc = w & 1;
  int m0 = blockIdx.y * BM, n0 = blockIdx.x * 128;
  f32x4 acc[RI][4] = {};

  int srow = tid >> 3;                   // 0..31 within a 32-row staging chunk
  int scg  = (tid & 7) ^ (srow & 7);     // pre-swizzled source col-group (rule #21)
  const bf16* Abase = A + (size_t)m0 * K + scg * 8;
  const bf16* Bbase = Bw + (size_t)n0 * K + scg * 8;

  auto stage = [&](int buf, int k0) {
    bf16* dA = sA + buf * (BM * 64);
    bf16* dB = sB + buf * (128 * 64);
    #pragma unroll
    for (int it = 0; it < RI; ++it) {
      int row = it * 32 + srow;
      gload16(Abase + (size_t)row * K + k0, dA + (it * 32 + (w << 3)) * 64);
    }
    #pragma unroll
    for (int it = 0; it < 4; ++it) {
      int row = it * 32 + srow;
      gload16(Bbase + (size_t)row * K + k0, dB + (it * 32 + (w << 3)) * 64);
    }
  };

  auto compute = [&](int buf) {
    const bf16* cA = sA + buf * (BM * 64);
    const bf16* cB = sB + buf * (128 * 64);
    #pragma unroll
    for (int kk = 0; kk < 2; ++kk) {
      bf16x8 av[RI], bv[4];
      #pragma unroll
      for (int i = 0; i < RI; ++i) {
        int ar = wr * (BM / 2) + i * 16 + (l & 15);
        int aq = ((kk << 2) + (l >> 4)) ^ (ar & 7);
        av[i] = *(const bf16x8*)&cA[ar * 64 + aq * 8];
      }
      #pragma unroll
      for (int j = 0; j < 4; ++j) {
        int br = wc * 64 + j * 16 + (l & 15);
        int bq = ((kk << 2) + (l >> 4)) ^ (br & 7);
        bv[j] = *(const bf16x8*)&cB[br * 64 + bq * 8];
      }
      #pragma unroll
      for (int i = 0; i < RI; ++i)
        #pragma unroll
        for (int j = 0; j < 4; ++j)
          acc[i][j] = __builtin_amdgcn_mfma_f32_16x16x32_bf16(av[i], bv[j], acc[i][j], 0, 0, 0);
    }
  };

  int NT = K >> 6;
  if (DBUF) {
    stage(0, 0);
    __syncthreads();
    for (int t = 0; t < NT; ++t) {
      if (t + 1 < NT) stage((t + 1) & 1, (t + 1) << 6);
      compute(t & 1);
      __syncthreads();
    }
  } else {
    for (int t = 0; t < NT; ++t) {
      __syncthreads();
      stage(0, t << 6);
      __syncthreads();
      compute(0);
    }
    __syncthreads();
  }

  // ---- coalesced epilogue: LDS transpose, then contiguous writes ----
  int wrg = tid >> 7;                    // reader: which wr half
  int rr  = (tid >> 3) & 15;             // reader: row within 16-row group
  int c16 = (tid & 7) * 16;              // reader: 16-col segment
  #pragma unroll
  for (int i = 0; i < RI; ++i) {
    #pragma unroll
    for (int j = 0; j < 4; ++j)
      #pragma unroll
      for (int e = 0; e < 4; ++e)
        ep[(wr * 16 + (l >> 4) * 4 + e) * EPS + wc * 64 + j * 16 + (l & 15)] = acc[i][j][e];
    __syncthreads();
    {
      int row = m0 + wrg * (BM / 2) + i * 16 + rr;
      int colb = n0 + c16;
      const float* src = &ep[(wrg * 16 + rr) * EPS + c16];
      float v[16];
      #pragma unroll
      for (int e = 0; e < 16; ++e) v[e] = src[e] + bias[colb + e];
      size_t idx = (size_t)row * N + colb;
      if (MODE == 0 || MODE == 1) {
        bf16x8 o0, o1;
        #pragma unroll
        for (int e = 0; e < 8; ++e) {
          float v0 = (MODE == 1) ? gelu_f(v[e]) : v[e];
          float v1 = (MODE == 1) ? gelu_f(v[8 + e]) : v[8 + e];
          o0[e] = (bf16)v0; o1[e] = (bf16)v1;
        }
        *(bf16x8*)(Cb + idx) = o0;
        *(bf16x8*)(Cb + idx + 8) = o1;
      } else if (MODE == 2) {
        #pragma unroll
        for (int q = 0; q < 4; ++q) {
          float4 c = *(float4*)(Cf + idx + q * 4);
          c.x += v[q * 4]; c.y += v[q * 4 + 1]; c.z += v[q * 4 + 2]; c.w += v[q * 4 + 3];
          *(float4*)(Cf + idx + q * 4) = c;
        }
      } else {
        int tloc = row % TT;
        const float* per = pe + (size_t)tloc * DD + colb;
        #pragma unroll
        for (int q = 0; q < 4; ++q) {
          float4 r = *(const float4*)(resid + idx + q * 4);
          float4 pv = *(const float4*)(per + q * 4);
          float4 o;
          o.x = r.x + gelu_f(v[q * 4])     + pv.x;
          o.y = r.y + gelu_f(v[q * 4 + 1]) + pv.y;
          o.z = r.z + gelu_f(v[q * 4 + 2]) + pv.z;
          o.w = r.w + gelu_f(v[q * 4 + 3]) + pv.w;
          *(float4*)(Cf + idx + q * 4) = o;
        }
      }
    }
    if (i + 1 < RI) __syncthreads();
  }
}

extern "C" void kernel_launch(void* const* d_in, const int* in_sizes, int n_in,
                              void* d_out, int out_size, void* d_ws, size_t ws_size,
                              hipStream_t stream) {
  const float* x     = (const float*)d_in[0];
  const float* dw_w  = (const float*)d_in[1];
  const float* dw_b  = (const float*)d_in[2];
  const float* pw_w  = (const float*)d_in[3];
  const float* pw_b  = (const float*)d_in[4];
  const float* Wqkv  = (const float*)d_in[5];
  const float* bqkv  = (const float*)d_in[6];
  const float* Wo    = (const float*)d_in[7];
  const float* bo    = (const float*)d_in[8];
  const float* ln1_w = (const float*)d_in[9];
  const float* ln1_b = (const float*)d_in[10];
  const float* ln2_w = (const float*)d_in[11];
  const float* ln2_b = (const float*)d_in[12];
  const float* W1    = (const float*)d_in[13];
  const float* b1    = (const float*)d_in[14];
  const float* W2    = (const float*)d_in[15];
  const float* b2    = (const float*)d_in[16];
  const unsigned char* pad = (const unsigned char*)d_in[17];
  float* xm = (float*)d_out;

  char* p = (char*)d_ws;
  auto alloc = [&](size_t bytes) {
    char* r = p;
    p += (bytes + 255) & ~(size_t)255;
    return r;
  };
  bf16* wb_pw  = (bf16*)alloc((size_t)DD * DD * 2);
  bf16* wb_qkv = (bf16*)alloc((size_t)LL * 3 * DD * DD * 2);
  bf16* wb_wo  = (bf16*)alloc((size_t)LL * DD * DD * 2);
  bf16* wb_w1  = (bf16*)alloc((size_t)LL * 4 * DD * DD * 2);
  bf16* wb_w2  = (bf16*)alloc((size_t)LL * 4 * DD * DD * 2);
  bf16* act    = (bf16*)alloc((size_t)MROWS * DD * 2);
  bf16* big    = (bf16*)alloc((size_t)MROWS * 4 * DD * 2);
  float* peb   = (float*)alloc((size_t)TT * DD * 4);

  auto cvt = [&](const float* src, bf16* dst, size_t n) {
    int n4 = (int)(n / 4);
    cvt_f2b<<<(n4 + 255) / 256, 256, 0, stream>>>(src, dst, n4);
  };
  cvt(pw_w, wb_pw, (size_t)DD * DD);
  cvt(Wqkv, wb_qkv, (size_t)LL * 3 * DD * DD);
  cvt(Wo,   wb_wo,  (size_t)LL * DD * DD);
  cvt(W1,   wb_w1,  (size_t)LL * 4 * DD * DD);
  cvt(W2,   wb_w2,  (size_t)LL * 4 * DD * DD);

  pe_kernel<<<(TT * (DD / 2) + 255) / 256, 256, 0, stream>>>(peb);
  conv_dw<<<(MROWS * DD / 4) / 256, 256, 0, stream>>>(x, dw_w, dw_b, act);

  // x = x_in + gelu(conv @ pw^T + pw_b) + pe   -> fp32 master in d_out
  gemm_bt<3, 64, true><<<dim3(DD / 128, MROWS / 64), 256, 0, stream>>>(
      act, wb_pw, pw_b, peb, x, xm, nullptr, MROWS, DD, DD);

  for (int layer = 0; layer < LL; ++layer) {
    ln_kernel<<<MROWS / 4, 256, 0, stream>>>(xm, ln1_w + layer * DD, ln1_b + layer * DD, act);
    gemm_bt<0, 128, false><<<dim3(3 * DD / 128, MROWS / 128), 256, 0, stream>>>(
        act, wb_qkv + (size_t)layer * 3 * DD * DD, bqkv + layer * 3 * DD,
        nullptr, nullptr, nullptr, big, MROWS, 3 * DD, DD);
    attn_kernel<<<(BB * HH * (TT / 8)) / 4, 256, 0, stream>>>(big, pad, act);
    gemm_bt<2, 64, true><<<dim3(DD / 128, MROWS / 64), 256, 0, stream>>>(
        act, wb_wo + (size_t)layer * DD * DD, bo + layer * DD,
        nullptr, nullptr, xm, nullptr, MROWS, DD, DD);
    ln_kernel<<<MROWS / 4, 256, 0, stream>>>(xm, ln2_w + layer * DD, ln2_b + layer * DD, act);
    gemm_bt<1, 128, false><<<dim3(4 * DD / 128, MROWS / 128), 256, 0, stream>>>(
        act, wb_w1 + (size_t)layer * 4 * DD * DD, b1 + layer * 4 * DD,
        nullptr, nullptr, nullptr, big, MROWS, 4 * DD, DD);
    gemm_bt<2, 64, true><<<dim3(DD / 128, MROWS / 64), 256, 0, stream>>>(
        big, wb_w2 + (size_t)layer * 4 * DD * DD, b2 + layer * DD,
        nullptr, nullptr, xm, nullptr, MROWS, DD, 4 * DD);
  }
}

// Round 6
// 758.125 us; speedup vs baseline: 1.1323x; 1.1323x over previous
//
#include <hip/hip_runtime.h>
#include <cstdint>
#include <cstddef>

#define BB 8
#define TT 1536
#define DD 512
#define HH 8
#define HDD 64
#define LL 4
#define MROWS (BB*TT)   // 12288

typedef __bf16 bf16;
typedef __bf16 bf16x8 __attribute__((ext_vector_type(8)));
typedef float f32x4 __attribute__((ext_vector_type(4)));

typedef void as1_void __attribute__((address_space(1)));
typedef void as3_void __attribute__((address_space(3)));

__device__ __forceinline__ void gload16(const bf16* g, bf16* l) {
  __builtin_amdgcn_global_load_lds((as1_void*)g, (as3_void*)l, 16, 0, 0);
}

__device__ __forceinline__ float gelu_f(float v) {
  return 0.5f * v * (1.0f + erff(v * 0.70710678118654752440f));
}

// ---------------- weight fp32 -> bf16 ----------------
__global__ void cvt_f2b(const float* __restrict__ in, bf16* __restrict__ out, int n4) {
  int i = blockIdx.x * blockDim.x + threadIdx.x;
  if (i >= n4) return;
  float4 v = ((const float4*)in)[i];
  union { bf16 h[4]; uint2 u; } p;
  p.h[0] = (bf16)v.x; p.h[1] = (bf16)v.y; p.h[2] = (bf16)v.z; p.h[3] = (bf16)v.w;
  ((uint2*)out)[i] = p.u;
}

// ---------------- sinusoidal PE table (T x D fp32) ----------------
__global__ void pe_kernel(float* __restrict__ pe) {
  int i = blockIdx.x * blockDim.x + threadIdx.x;   // over T*(D/2)
  if (i >= TT * (DD / 2)) return;
  int t = i / (DD / 2), k = i % (DD / 2);
  float div = expf((2.0f * (float)k) * (-9.210340371976184f / (float)DD));
  float ang = (float)t * div;
  pe[(size_t)t * DD + 2 * k]     = sinf(ang);
  pe[(size_t)t * DD + 2 * k + 1] = cosf(ang);
}

// ---------------- depthwise conv k=5 pad=2 (+bias) -> bf16, float4 ----------------
__global__ void conv_dw(const float* __restrict__ x, const float* __restrict__ kw,
                        const float* __restrict__ kb, bf16* __restrict__ out) {
  int idx = blockIdx.x * 256 + threadIdx.x;        // over B*T*(D/4)
  int d4 = idx & (DD / 4 - 1);
  int bt = idx >> 7;                               // D/4=128
  int t = bt % TT;
  float4 acc = ((const float4*)kb)[d4];
  #pragma unroll
  for (int w = 0; w < 5; ++w) {
    int tt = t + w - 2;
    if (tt >= 0 && tt < TT) {
      float4 xv = ((const float4*)(x + (size_t)(bt + (w - 2)) * DD))[d4];
      float4 kv = ((const float4*)(kw + w * DD))[d4];
      acc.x += xv.x * kv.x; acc.y += xv.y * kv.y;
      acc.z += xv.z * kv.z; acc.w += xv.w * kv.w;
    }
  }
  union { bf16 h[4]; uint2 u; } p;
  p.h[0] = (bf16)acc.x; p.h[1] = (bf16)acc.y; p.h[2] = (bf16)acc.z; p.h[3] = (bf16)acc.w;
  ((uint2*)out)[idx] = p.u;
}

// ---------------- LayerNorm (row=512) fp32 -> bf16, wave per row ----------------
__global__ __launch_bounds__(256) void ln_kernel(const float* __restrict__ x,
    const float* __restrict__ w, const float* __restrict__ b, bf16* __restrict__ y) {
  int l = threadIdx.x & 63;
  int row = blockIdx.x * 4 + (threadIdx.x >> 6);
  const float4* xr = (const float4*)(x + (size_t)row * DD);
  union F8 { float4 v[2]; float f[8]; };
  F8 xv, wv, bv;
  xv.v[0] = xr[l * 2]; xv.v[1] = xr[l * 2 + 1];
  float s = 0.f, q = 0.f;
  #pragma unroll
  for (int e = 0; e < 8; ++e) { s += xv.f[e]; q += xv.f[e] * xv.f[e]; }
  #pragma unroll
  for (int off = 1; off < 64; off <<= 1) {
    s += __shfl_xor(s, off);
    q += __shfl_xor(q, off);
  }
  float mean = s * (1.0f / DD);
  float var  = q * (1.0f / DD) - mean * mean;
  float rstd = rsqrtf(var + 1e-5f);
  const float4* wr = (const float4*)w;
  const float4* br = (const float4*)b;
  wv.v[0] = wr[l * 2]; wv.v[1] = wr[l * 2 + 1];
  bv.v[0] = br[l * 2]; bv.v[1] = br[l * 2 + 1];
  bf16x8 o;
  #pragma unroll
  for (int e = 0; e < 8; ++e)
    o[e] = (bf16)((xv.f[e] - mean) * rstd * wv.f[e] + bv.f[e]);
  *(bf16x8*)(y + (size_t)row * DD + l * 8) = o;
}

// ---------------- sliding-window attention ----------------
__global__ __launch_bounds__(256) void attn_kernel(const bf16* __restrict__ qkv,
    const unsigned char* __restrict__ pad, bf16* __restrict__ o) {
  int l = threadIdx.x & 63;
  int wv = blockIdx.x * 4 + (threadIdx.x >> 6);    // over B*H*(T/8)
  int g = l >> 3, s = l & 7;
  int tb = wv % (TT / 8);
  int bh = wv / (TT / 8);
  int h = bh & (HH - 1);
  int b = bh >> 3;
  int t = tb * 8 + g;
  const float scale = 0.125f;                      // 1/sqrt(64)
  const bf16* base = qkv + (size_t)(b * TT) * (3 * DD) + h * HDD + s * 8;

  float q[8];
  {
    bf16x8 qv = *(const bf16x8*)(base + (size_t)t * (3 * DD));
    #pragma unroll
    for (int e = 0; e < 8; ++e) q[e] = (float)qv[e] * scale;
  }
  float sc[11];
  #pragma unroll
  for (int jj = 0; jj < 11; ++jj) {
    int j = t - 5 + jj;
    bool ok = (j >= 0) && (j < TT);
    int jc = ok ? j : t;
    bf16x8 kv = *(const bf16x8*)(base + (size_t)jc * (3 * DD) + DD);
    float sv = 0.f;
    #pragma unroll
    for (int e = 0; e < 8; ++e) sv += q[e] * (float)kv[e];
    sv += __shfl_xor(sv, 1);
    sv += __shfl_xor(sv, 2);
    sv += __shfl_xor(sv, 4);
    if (pad[b * TT + jc]) sv -= 1e9f;
    sc[jj] = ok ? sv : -3.0e38f;
  }
  float m = sc[0];
  #pragma unroll
  for (int jj = 1; jj < 11; ++jj) m = fmaxf(m, sc[jj]);
  float den = 0.f;
  float acc[8] = {};
  #pragma unroll
  for (int jj = 0; jj < 11; ++jj) {
    float p = __expf(sc[jj] - m);
    den += p;
    int j = t - 5 + jj;
    int jc = (j >= 0 && j < TT) ? j : t;
    bf16x8 vv = *(const bf16x8*)(base + (size_t)jc * (3 * DD) + 2 * DD);
    #pragma unroll
    for (int e = 0; e < 8; ++e) acc[e] += p * (float)vv[e];
  }
  float rd = 1.0f / den;
  bf16x8 ov;
  #pragma unroll
  for (int e = 0; e < 8; ++e) ov[e] = (bf16)(acc[e] * rd);
  *(bf16x8*)(o + (size_t)(b * TT + t) * DD + h * HDD + s * 8) = ov;
}

// ---------------- bf16 MFMA GEMM: C = A[M][K] * Bw[N][K]^T (+epilogue) ----------------
// Tile BM x 128, BK=64, 4 waves (2x2). DBUF: 2-phase double-buffered staging (48KB for BM=64).
// XCD-aware block remap: all N-band blocks of one A m-band land on the same XCD
// (A band fetched into exactly one per-XCD L2; bijective since gridDim.y % 8 == 0).
// MODE 0: Cb = acc + bias                    (bf16 out)
// MODE 1: Cb = gelu(acc + bias)              (bf16 out)
// MODE 2: Cf += acc + bias                   (fp32 master, in-place RMW)
// MODE 3: Cf = resid + gelu(acc+bias) + pe   (fp32 master init; pointwise front-end)
template<int MODE, int BM, bool DBUF>
__global__ __launch_bounds__(256) void gemm_bt(
    const bf16* __restrict__ A, const bf16* __restrict__ Bw,
    const float* __restrict__ bias, const float* __restrict__ pe,
    const float* __restrict__ resid, float* __restrict__ Cf, bf16* __restrict__ Cb,
    int M, int N, int K)
{
  constexpr int RI = BM / 32;            // 16x16 row-fragments per wave
  constexpr int NB = DBUF ? 2 : 1;
  __shared__ bf16 sA[NB * BM * 64];
  __shared__ bf16 sB[NB * 128 * 64];
  int tid = threadIdx.x;
  int w = tid >> 6, l = tid & 63;
  int wr = w >> 1, wc = w & 1;

  // XCD-aware remap: lin = (by%8) + 8*(bx + GX*(by/8))
  int lin = blockIdx.x + gridDim.x * blockIdx.y;
  int GX = gridDim.x;
  int r8 = lin & 7, q8 = lin >> 3;
  int bx = q8 % GX;
  int by = r8 + 8 * (q8 / GX);
  int m0 = by * BM, n0 = bx * 128;
  f32x4 acc[RI][4] = {};

  int srow = tid >> 3;                   // 0..31 within a 32-row staging chunk
  int scg  = (tid & 7) ^ (srow & 7);     // pre-swizzled source col-group (rule #21)
  const bf16* Abase = A + (size_t)m0 * K + scg * 8;
  const bf16* Bbase = Bw + (size_t)n0 * K + scg * 8;

  auto stage = [&](int buf, int k0) {
    bf16* dA = sA + buf * (BM * 64);
    bf16* dB = sB + buf * (128 * 64);
    #pragma unroll
    for (int it = 0; it < RI; ++it) {
      int row = it * 32 + srow;
      gload16(Abase + (size_t)row * K + k0, dA + (it * 32 + (w << 3)) * 64);
    }
    #pragma unroll
    for (int it = 0; it < 4; ++it) {
      int row = it * 32 + srow;
      gload16(Bbase + (size_t)row * K + k0, dB + (it * 32 + (w << 3)) * 64);
    }
  };

  auto compute = [&](int buf) {
    const bf16* cA = sA + buf * (BM * 64);
    const bf16* cB = sB + buf * (128 * 64);
    #pragma unroll
    for (int kk = 0; kk < 2; ++kk) {
      bf16x8 av[RI], bv[4];
      #pragma unroll
      for (int i = 0; i < RI; ++i) {
        int ar = wr * (BM / 2) + i * 16 + (l & 15);
        int aq = ((kk << 2) + (l >> 4)) ^ (ar & 7);
        av[i] = *(const bf16x8*)&cA[ar * 64 + aq * 8];
      }
      #pragma unroll
      for (int j = 0; j < 4; ++j) {
        int br = wc * 64 + j * 16 + (l & 15);
        int bq = ((kk << 2) + (l >> 4)) ^ (br & 7);
        bv[j] = *(const bf16x8*)&cB[br * 64 + bq * 8];
      }
      #pragma unroll
      for (int i = 0; i < RI; ++i)
        #pragma unroll
        for (int j = 0; j < 4; ++j)
          acc[i][j] = __builtin_amdgcn_mfma_f32_16x16x32_bf16(av[i], bv[j], acc[i][j], 0, 0, 0);
    }
  };

  int NT = K >> 6;
  if (DBUF) {
    stage(0, 0);
    __syncthreads();
    for (int t = 0; t < NT; ++t) {
      if (t + 1 < NT) stage((t + 1) & 1, (t + 1) << 6);
      compute(t & 1);
      __syncthreads();
    }
  } else {
    for (int t = 0; t < NT; ++t) {
      __syncthreads();
      stage(0, t << 6);
      __syncthreads();
      compute(0);
    }
  }

  // epilogue — C/D layout: col = lane&15, row = (lane>>4)*4 + reg
  int r0 = m0 + wr * (BM / 2) + ((l >> 4) << 2);
  int c0 = n0 + wc * 64 + (l & 15);
  #pragma unroll
  for (int i = 0; i < RI; ++i) {
    #pragma unroll
    for (int j = 0; j < 4; ++j) {
      int col = c0 + j * 16;
      float bsv = bias[col];
      #pragma unroll
      for (int e = 0; e < 4; ++e) {
        int row = r0 + i * 16 + e;
        size_t idx = (size_t)row * N + col;
        float v = acc[i][j][e] + bsv;
        if (MODE == 0) {
          Cb[idx] = (bf16)v;
        } else if (MODE == 1) {
          Cb[idx] = (bf16)gelu_f(v);
        } else if (MODE == 2) {
          Cf[idx] = Cf[idx] + v;
        } else {
          int tloc = row % TT;
          Cf[idx] = resid[idx] + gelu_f(v) + pe[(size_t)tloc * DD + col];
        }
      }
    }
  }
}

extern "C" void kernel_launch(void* const* d_in, const int* in_sizes, int n_in,
                              void* d_out, int out_size, void* d_ws, size_t ws_size,
                              hipStream_t stream) {
  const float* x     = (const float*)d_in[0];
  const float* dw_w  = (const float*)d_in[1];
  const float* dw_b  = (const float*)d_in[2];
  const float* pw_w  = (const float*)d_in[3];
  const float* pw_b  = (const float*)d_in[4];
  const float* Wqkv  = (const float*)d_in[5];
  const float* bqkv  = (const float*)d_in[6];
  const float* Wo    = (const float*)d_in[7];
  const float* bo    = (const float*)d_in[8];
  const float* ln1_w = (const float*)d_in[9];
  const float* ln1_b = (const float*)d_in[10];
  const float* ln2_w = (const float*)d_in[11];
  const float* ln2_b = (const float*)d_in[12];
  const float* W1    = (const float*)d_in[13];
  const float* b1    = (const float*)d_in[14];
  const float* W2    = (const float*)d_in[15];
  const float* b2    = (const float*)d_in[16];
  const unsigned char* pad = (const unsigned char*)d_in[17];
  float* xm = (float*)d_out;

  char* p = (char*)d_ws;
  auto alloc = [&](size_t bytes) {
    char* r = p;
    p += (bytes + 255) & ~(size_t)255;
    return r;
  };
  bf16* wb_pw  = (bf16*)alloc((size_t)DD * DD * 2);
  bf16* wb_qkv = (bf16*)alloc((size_t)LL * 3 * DD * DD * 2);
  bf16* wb_wo  = (bf16*)alloc((size_t)LL * DD * DD * 2);
  bf16* wb_w1  = (bf16*)alloc((size_t)LL * 4 * DD * DD * 2);
  bf16* wb_w2  = (bf16*)alloc((size_t)LL * 4 * DD * DD * 2);
  bf16* act    = (bf16*)alloc((size_t)MROWS * DD * 2);
  bf16* big    = (bf16*)alloc((size_t)MROWS * 4 * DD * 2);
  float* peb   = (float*)alloc((size_t)TT * DD * 4);

  auto cvt = [&](const float* src, bf16* dst, size_t n) {
    int n4 = (int)(n / 4);
    cvt_f2b<<<(n4 + 255) / 256, 256, 0, stream>>>(src, dst, n4);
  };
  cvt(pw_w, wb_pw, (size_t)DD * DD);
  cvt(Wqkv, wb_qkv, (size_t)LL * 3 * DD * DD);
  cvt(Wo,   wb_wo,  (size_t)LL * DD * DD);
  cvt(W1,   wb_w1,  (size_t)LL * 4 * DD * DD);
  cvt(W2,   wb_w2,  (size_t)LL * 4 * DD * DD);

  pe_kernel<<<(TT * (DD / 2) + 255) / 256, 256, 0, stream>>>(peb);
  conv_dw<<<(MROWS * DD / 4) / 256, 256, 0, stream>>>(x, dw_w, dw_b, act);

  // x = x_in + gelu(conv @ pw^T + pw_b) + pe   -> fp32 master in d_out
  gemm_bt<3, 64, true><<<dim3(DD / 128, MROWS / 64), 256, 0, stream>>>(
      act, wb_pw, pw_b, peb, x, xm, nullptr, MROWS, DD, DD);

  for (int layer = 0; layer < LL; ++layer) {
    ln_kernel<<<MROWS / 4, 256, 0, stream>>>(xm, ln1_w + layer * DD, ln1_b + layer * DD, act);
    gemm_bt<0, 128, false><<<dim3(3 * DD / 128, MROWS / 128), 256, 0, stream>>>(
        act, wb_qkv + (size_t)layer * 3 * DD * DD, bqkv + layer * 3 * DD,
        nullptr, nullptr, nullptr, big, MROWS, 3 * DD, DD);
    attn_kernel<<<(BB * HH * (TT / 8)) / 4, 256, 0, stream>>>(big, pad, act);
    gemm_bt<2, 64, true><<<dim3(DD / 128, MROWS / 64), 256, 0, stream>>>(
        act, wb_wo + (size_t)layer * DD * DD, bo + layer * DD,
        nullptr, nullptr, xm, nullptr, MROWS, DD, DD);
    ln_kernel<<<MROWS / 4, 256, 0, stream>>>(xm, ln2_w + layer * DD, ln2_b + layer * DD, act);
    gemm_bt<1, 128, false><<<dim3(4 * DD / 128, MROWS / 128), 256, 0, stream>>>(
        act, wb_w1 + (size_t)layer * 4 * DD * DD, b1 + layer * 4 * DD,
        nullptr, nullptr, nullptr, big, MROWS, 4 * DD, DD);
    gemm_bt<2, 64, true><<<dim3(DD / 128, MROWS / 64), 256, 0, stream>>>(
        big, wb_w2 + (size_t)layer * 4 * DD * DD, b2 + layer * DD,
        nullptr, nullptr, xm, nullptr, MROWS, DD, 4 * DD);
  }
}